// Round 1
// baseline (226.425 us; speedup 1.0000x reference)
//
#include <hip/hip_runtime.h>
#include <math.h>

#define NDIRS 64
#define DD 64
#define NBIN 65          // num_steps + 1
#define THREADS 128
#define SLABS 16
#define IPLANES 4        // DD / SLABS

// dh = 2*sqrt(3); INV = 1/dh. min_h = -32*dh exactly, so bin = 32 + ceil(h*INV).
static constexpr float INV = 0.28867513459481287f;

__global__ __launch_bounds__(THREADS) void wect_hist_kernel(
    const float* __restrict__ x, const float* __restrict__ dirs,
    float* __restrict__ ph) {
  __shared__ float hist[THREADS * NBIN];
  const int k = blockIdx.x;
  const int slab = blockIdx.y;
  const int tid = threadIdx.x;

  for (int i = tid; i < THREADS * NBIN; i += THREADS) hist[i] = 0.0f;
  __syncthreads();

  const float d0 = dirs[3 * k + 0];
  const float d1 = dirs[3 * k + 1];
  const float d2 = dirs[3 * k + 2];
  // relu offsets, pre-scaled by 1/dh; each <= 1/(2) total sum <= 0.5
  const float q0 = fmaxf(d0, 0.0f) * INV;
  const float q1 = fmaxf(d1, 0.0f) * INV;
  const float q2 = fmaxf(d2, 0.0f) * INV;
  const float q12 = q1 + q2;
  const float q02 = q0 + q2;
  const float q01 = q0 + q1;
  const float q012 = q0 + q1 + q2;

  float* __restrict__ myh = &hist[tid * NBIN];
  const int i0 = slab * IPLANES;
  const float* __restrict__ xs = x + i0 * (DD * DD);

  for (int c = tid; c < IPLANES * DD * DD; c += THREADS) {
    const int l = c & 63;
    const int j = (c >> 6) & 63;
    const int i = i0 + (c >> 12);
    const int dL = (l < 63) ? 1 : 0;
    const int dJ = (j < 63) ? 64 : 0;
    const int dI = (i < 63) ? 4096 : 0;
    const bool iv = dI != 0, jv = dJ != 0, lv = dL != 0;

    const float* p = xs + c;
    const float x000 = p[0];
    const float x001 = p[dL];
    const float x010 = p[dJ];
    const float x011 = p[dJ + dL];
    const float x100 = p[dI];
    const float x101 = p[dI + dL];
    const float x110 = p[dI + dJ];
    const float x111 = p[dI + dJ + dL];

    // pairmax values (boundary-invalid ones masked to 0 below)
    const float e0 = fmaxf(x000, x100);
    const float e1 = fmaxf(x000, x010);
    const float e2 = fmaxf(x000, x001);
    const float s12 = fmaxf(fmaxf(e1, x001), x011);
    const float s02 = fmaxf(fmaxf(e0, x001), x101);
    const float s01 = fmaxf(fmaxf(e0, x010), x110);
    const float cc  = fmaxf(fmaxf(s01, fmaxf(x001, x101)), fmaxf(x011, x111));

    const float h = d0 * (float)i + d1 * (float)j + d2 * (float)l;
    const float u0 = h * INV;
    const float b0f = ceilf(u0);
    const float fr = b0f - u0;        // in [0,1): threshold for bumping to bin+1
    int ib0 = (int)b0f + 32;
    ib0 = max(0, min(64, ib0));
    const int ib1 = min(ib0 + 1, 64);

    // accumulate signed totals: T = all items, S = items spilling into bin+1
    float T = x000;                    // vertex: offset 0, never spills
    float S = 0.0f;
    float sv;
    sv = iv ? -e0 : 0.0f;                T += sv; S += (q0   > fr) ? sv : 0.0f;
    sv = jv ? -e1 : 0.0f;                T += sv; S += (q1   > fr) ? sv : 0.0f;
    sv = lv ? -e2 : 0.0f;                T += sv; S += (q2   > fr) ? sv : 0.0f;
    sv = (jv && lv) ? s12 : 0.0f;        T += sv; S += (q12  > fr) ? sv : 0.0f;
    sv = (iv && lv) ? s02 : 0.0f;        T += sv; S += (q02  > fr) ? sv : 0.0f;
    sv = (iv && jv) ? s01 : 0.0f;        T += sv; S += (q01  > fr) ? sv : 0.0f;
    sv = (iv && jv && lv) ? -cc : 0.0f;  T += sv; S += (q012 > fr) ? sv : 0.0f;

    atomicAdd(&myh[ib0], T - S);   // private row: ds_add_f32, no contention
    atomicAdd(&myh[ib1], S);
  }

  __syncthreads();
  // column reduce: thread t sums bin t across all 128 private rows
  if (tid < NBIN) {
    float s = 0.0f;
    #pragma unroll 8
    for (int r = 0; r < THREADS; ++r) s += hist[r * NBIN + tid];
    ph[(slab * NDIRS + k) * NBIN + tid] = s;   // deterministic partials, no atomics
  }
}

__global__ __launch_bounds__(128) void wect_scan_kernel(
    const float* __restrict__ ph, float* __restrict__ out) {
  __shared__ float s[NBIN];
  const int k = blockIdx.x;
  const int t = threadIdx.x;
  if (t < NBIN) {
    float v = 0.0f;
    #pragma unroll
    for (int sl = 0; sl < SLABS; ++sl) v += ph[(sl * NDIRS + k) * NBIN + t];
    s[t] = v;
  }
  __syncthreads();
  // Hillis-Steele inclusive scan over 65 bins
  for (int off = 1; off < NBIN; off <<= 1) {
    float a = 0.0f;
    if (t < NBIN && t >= off) a = s[t - off];
    __syncthreads();
    if (t < NBIN && t >= off) s[t] += a;
    __syncthreads();
  }
  if (t < NBIN) out[k * NBIN + t] = s[t];
}

extern "C" void kernel_launch(void* const* d_in, const int* in_sizes, int n_in,
                              void* d_out, int out_size, void* d_ws, size_t ws_size,
                              hipStream_t stream) {
  const float* x = (const float*)d_in[0];
  const float* dirs = (const float*)d_in[1];
  float* out = (float*)d_out;
  float* ph = (float*)d_ws;   // SLABS*NDIRS*NBIN floats = 266,240 B

  wect_hist_kernel<<<dim3(NDIRS, SLABS), THREADS, 0, stream>>>(x, dirs, ph);
  wect_scan_kernel<<<NDIRS, 128, 0, stream>>>(ph, out);
}